// Round 13
// baseline (110.245 us; speedup 1.0000x reference)
//
#include <hip/hip_runtime.h>
#include <hip/hip_bf16.h>

// Problem constants (fixed by the reference): B=4, H=16, S=1024, D=64.
#define B_N 4
#define H_N 16
#define S_N 1024
#define D_N 64
#define NELEM (B_N * H_N * S_N * D_N)   // 4194304 elements per tensor

typedef __bf16 bf16;
typedef bf16  bf16x4 __attribute__((ext_vector_type(4)));
typedef bf16  bf16x8 __attribute__((ext_vector_type(8)));
typedef float f32x4  __attribute__((ext_vector_type(4)));
typedef unsigned int u32x2 __attribute__((ext_vector_type(2)));

#define AS1 __attribute__((address_space(1)))
#define AS3 __attribute__((address_space(3)))
// global->LDS DMA, 16B per lane; LDS dest = wave-uniform base + lane*16 (m104)
#define GLL16(gp, lp) __builtin_amdgcn_global_load_lds((const AS1 void*)(gp), (AS3 void*)(lp), 16, 0, 0)

// ============================================================================
// Prep: fp32 -> bf16 swizzled copies of K and V into d_ws.
//  Kb[bh][k][d]   16B slots within each 128B row XORed by (k&7)  [unchanged]
//  Vt[bh][d][k]   transposed; k grouped in 32-k tiles of 4 8-k slots; slot
//                 position = slot ^ ((d>>1)&3)  [matched to 64B-row LDS reads]
// ============================================================================
__global__ __launch_bounds__(256)
void prep_kv(const float* __restrict__ K, const float* __restrict__ V,
             bf16* __restrict__ Kb, bf16* __restrict__ Vt)
{
    const int b = blockIdx.x;
    if (b < 2048) {                        // ---- K: swizzled bf16 copy ----
        int t = b * 256 + threadIdx.x;     // 8 elems per thread
        int row = t >> 3, sub = t & 7;     // row = bh*S + k; sub = 16B slot
        const float* src = K + (size_t)row * 64 + sub * 8;
        float4 f0 = *(const float4*)src;
        float4 f1 = *(const float4*)(src + 4);
        bf16x8 o;
        o[0] = (bf16)f0.x; o[1] = (bf16)f0.y; o[2] = (bf16)f0.z; o[3] = (bf16)f0.w;
        o[4] = (bf16)f1.x; o[5] = (bf16)f1.y; o[6] = (bf16)f1.z; o[7] = (bf16)f1.w;
        int slot = sub ^ (row & 7);
        *(bf16x8*)(Kb + (size_t)row * 64 + slot * 8) = o;
    } else {                               // ---- V: transpose + swizzle ----
        int wid  = (b - 2048) * 4 + (threadIdx.x >> 6);
        int lane = threadIdx.x & 63;       // lane = d
        int bh = wid >> 7, chunk = wid & 127;   // 128 chunks of 8 k-rows
        const float* src = V + (size_t)bh * S_N * D_N + (size_t)chunk * 8 * 64 + lane;
        bf16x8 o;
#pragma unroll
        for (int j = 0; j < 8; ++j) o[j] = (bf16)src[j * 64];
        // 32-k tile = chunk>>2; slot within tile = chunk&3, placed at
        // position (chunk&3) ^ ((d>>1)&3)  (read side XORs the same bits)
        int s = (chunk & 3) ^ ((lane >> 1) & 3);
        bf16* dst = Vt + (size_t)bh * D_N * S_N + (size_t)lane * S_N
                       + (chunk >> 2) * 32 + s * 8;
        *(bf16x8*)dst = o;
    }
}

// ============================================================================
// Main fused kernel — round 13: QB=32 (2 waves), KB=32, 18KB LDS ->
// 8 blocks/CU resident (was grid-capped at 4): 2x the independent chains,
// half-length iterations, 2-wave barriers. Compute bodies = round-9 patterns.
// ============================================================================
__global__ __launch_bounds__(128)
void sdpa_main(const float* __restrict__ Qf, const bf16* __restrict__ Kb,
               const bf16* __restrict__ Vt, float* __restrict__ Og,
               float* __restrict__ Pg)
{
    __shared__ __attribute__((aligned(128))) bf16 K_lds[2][2048];   // 2 x 4KB
    __shared__ __attribute__((aligned(128))) bf16 V_lds[2][2048];   // 2 x 4KB
    __shared__ __attribute__((aligned(128))) bf16 Pt_lds[2][512];   // 2 x 1KB

    // XCD-bijective swizzle (nwg=2048, 2048%8==0): 32 q-tiles/bh on one XCD
    const int bid = blockIdx.x;
    const int swz = (bid & 7) * 256 + (bid >> 3);
    const int bh = swz >> 5, qtile = swz & 31;

    const int tid = threadIdx.x;
    const int wave = tid >> 6, lane = tid & 63;   // wave 0..1
    const int l16 = lane & 15, lgrp = lane >> 4;
    const int swx = (l16 & 7) << 4;     // K-row (128B) XOR swizzle

    const float* Qp = Qf + (size_t)bh * S_N * D_N;
    const bf16* Kp = Kb + (size_t)bh * S_N * D_N;
    const bf16* Vp = Vt + (size_t)bh * D_N * S_N;
    float* Op = Og + (size_t)bh * S_N * D_N;
    float* Pp = Pg + (size_t)bh * S_N * S_N;

    // Q A-fragments from fp32, scaled by 1/sqrt(64): a[j]=Q[q=l16][k=lgrp*8+j]
    const int qrow = qtile * 32 + wave * 16 + l16;
    bf16x8 aq[2];
#pragma unroll
    for (int ds = 0; ds < 2; ++ds) {
        const float* src = Qp + (size_t)qrow * 64 + ds * 32 + lgrp * 8;
        float4 f0 = *(const float4*)src;
        float4 f1 = *(const float4*)(src + 4);
        aq[ds][0] = (bf16)(f0.x * 0.125f); aq[ds][1] = (bf16)(f0.y * 0.125f);
        aq[ds][2] = (bf16)(f0.z * 0.125f); aq[ds][3] = (bf16)(f0.w * 0.125f);
        aq[ds][4] = (bf16)(f1.x * 0.125f); aq[ds][5] = (bf16)(f1.y * 0.125f);
        aq[ds][6] = (bf16)(f1.z * 0.125f); aq[ds][7] = (bf16)(f1.w * 0.125f);
    }

    // Staging: one 32x64 K tile = 4KB = 2 GLL16 per wave (2 waves)
    auto stage_k = [&](int kt, bf16* dst) {
        const bf16* gk = Kp + (size_t)kt * 64;
        GLL16(gk + (wave    ) * 512 + lane * 8, dst + (wave    ) * 512);
        GLL16(gk + (wave + 2) * 512 + lane * 8, dst + (wave + 2) * 512);
    };
    // V tile [64 d][32 k] = 4KB; rows are d (64B each); lane = (d-row, 16B slot)
    auto stage_v = [&](int kt, bf16* dst) {
        const int dr = lane >> 2, c = lane & 3;
        GLL16(Vp + (size_t)(wave * 16 + dr     ) * S_N + kt + c * 8, dst + wave * 512);
        GLL16(Vp + (size_t)(wave * 16 + dr + 32) * S_N + kt + c * 8, dst + 1024 + wave * 512);
    };

    // QK^T scores: wave's 16 q-rows vs staged 32-row K tile (2 x 16-k blocks).
    // C/D layout (m89): col(k) = lane&15, row(q) = (lane>>4)*4 + reg.
    auto scores = [&](const bf16* base, f32x4 (&acc)[2]) {
#pragma unroll
        for (int kb = 0; kb < 2; ++kb) {
            acc[kb] = (f32x4){0.f, 0.f, 0.f, 0.f};
#pragma unroll
            for (int ds = 0; ds < 2; ++ds) {
                bf16x8 bk = *(const bf16x8*)((const char*)base
                            + (kb * 16 + l16) * 128
                            + ((ds * 64 + lgrp * 16) ^ swx));
                acc[kb] = __builtin_amdgcn_mfma_f32_16x16x32_bf16(aq[ds], bk, acc[kb], 0, 0, 0);
            }
        }
    };

    // -------- Pass A: denominators. 64 k per iter via 4-buffer ring. --------
    float lsum[4] = {0.f, 0.f, 0.f, 0.f};
    stage_k(0, &K_lds[0][0]);
    stage_k(32, &K_lds[1][0]);
    __syncthreads();
    for (int c = 0; c < 16; ++c) {
        const bf16* b0 = (c & 1) ? &V_lds[0][0] : &K_lds[0][0];
        const bf16* b1 = (c & 1) ? &V_lds[1][0] : &K_lds[1][0];
        bf16* n0 = (c & 1) ? &K_lds[0][0] : &V_lds[0][0];
        bf16* n1 = (c & 1) ? &K_lds[1][0] : &V_lds[1][0];
        if (c < 15) { stage_k((c + 1) * 64, n0); stage_k((c + 1) * 64 + 32, n1); }
        f32x4 acc[2];
        scores(b0, acc);
#pragma unroll
        for (int kb = 0; kb < 2; ++kb)
#pragma unroll
            for (int r = 0; r < 4; ++r) lsum[r] += __expf(acc[kb][r]);
        scores(b1, acc);
#pragma unroll
        for (int kb = 0; kb < 2; ++kb)
#pragma unroll
            for (int r = 0; r < 4; ++r) lsum[r] += __expf(acc[kb][r]);
        __syncthreads();   // joins waves AND drains vmcnt -> prefetch complete
    }
    float rl[4];
#pragma unroll
    for (int r = 0; r < 4; ++r) {
        float s = lsum[r];
        s += __shfl_xor(s, 1, 64);
        s += __shfl_xor(s, 2, 64);
        s += __shfl_xor(s, 4, 64);
        s += __shfl_xor(s, 8, 64);
        rl[r] = 1.0f / s;
    }

    // ---- Pass B: recompute, write P, accumulate O = P V. 32 iters, --------
    // ---- 1 counted-vmcnt barrier per iter (P stores stay in flight). ------
    f32x4 oacc[4];
#pragma unroll
    for (int db = 0; db < 4; ++db) oacc[db] = (f32x4){0.f, 0.f, 0.f, 0.f};

    const unsigned ptoff = (unsigned)(uintptr_t)(AS3 bf16*)(&Pt_lds[wave][0]);
    const int qg = qtile * 32 + wave * 16 + l16;

    stage_k(0, &K_lds[0][0]);
    stage_v(0, &V_lds[0][0]);
    asm volatile("s_waitcnt vmcnt(0)" ::: "memory");
    __builtin_amdgcn_s_barrier();
    for (int t = 0; t < 32; ++t) {
        const int kt = t * 32, buf = t & 1;

        f32x4 acc[2];
        scores(&K_lds[buf][0], acc);

        // Prefetch t+1 (issued before this iter's P stores; in-order vmcnt
        // lets the barrier wait complete staging without draining stores).
        if (t < 31) {
            stage_k(kt + 32, &K_lds[buf ^ 1][0]);
            stage_v(kt + 32, &V_lds[buf ^ 1][0]);
        }

        // p = exp(s)*rl -> bf16; write P^T[k][q] rows (32B) as 4-q ds_write_b64
#pragma unroll
        for (int kb = 0; kb < 2; ++kb) {
            bf16x4 pk;
#pragma unroll
            for (int r = 0; r < 4; ++r) pk[r] = (bf16)(__expf(acc[kb][r]) * rl[r]);
            *(bf16x4*)((char*)&Pt_lds[wave][0] + (kb * 16 + l16) * 32 + lgrp * 8) = pk;
        }
        asm volatile("s_waitcnt lgkmcnt(0)" ::: "memory");  // writes done before tr reads

        const bf16* vb = &V_lds[buf][0];
        // V B-fragments: row = db*16+l16 (64B rows), slot XOR by (row>>1)&3
        bf16x8 bv0, bv1, bv2, bv3;
        {
            const int vsw = ((l16 >> 1) & 3) << 4;   // (row>>1)&3 == (l16>>1)&3
            bv0 = *(const bf16x8*)((const char*)vb + (l16     ) * 64 + ((lgrp * 16) ^ vsw));
            bv1 = *(const bf16x8*)((const char*)vb + (16 + l16) * 64 + ((lgrp * 16) ^ vsw));
            bv2 = *(const bf16x8*)((const char*)vb + (32 + l16) * 64 + ((lgrp * 16) ^ vsw));
            bv3 = *(const bf16x8*)((const char*)vb + (48 + l16) * 64 + ((lgrp * 16) ^ vsw));
        }

        // PV A-fragment via HW transpose read (region per 16-lane group,
        // per-lane addr slot (addr&127)>>3 picks column q=l16).
        u32x2 t0, t1;
        unsigned a = ptoff + lgrp * 256 + l16 * 8;
        asm volatile("ds_read_b64_tr_b16 %0, %2\n\t"
                     "ds_read_b64_tr_b16 %1, %2 offset:128"
                     : "=&v"(t0), "=&v"(t1) : "v"(a));
        asm volatile("s_waitcnt lgkmcnt(0)" ::: "memory");
        __builtin_amdgcn_sched_barrier(0);   // rule 18: keep MFMA below the wait

        bf16x8 ap;
        ((unsigned*)&ap)[0] = t0[0]; ((unsigned*)&ap)[1] = t0[1];
        ((unsigned*)&ap)[2] = t1[0]; ((unsigned*)&ap)[3] = t1[1];

        // Global P store: lane holds 8 contiguous k for row q=l16 -> 2x f32x4
        float4 o0, o1;
        o0.x = __uint_as_float(t0[0] << 16);
        o0.y = __uint_as_float(t0[0] & 0xffff0000u);
        o0.z = __uint_as_float(t0[1] << 16);
        o0.w = __uint_as_float(t0[1] & 0xffff0000u);
        o1.x = __uint_as_float(t1[0] << 16);
        o1.y = __uint_as_float(t1[0] & 0xffff0000u);
        o1.z = __uint_as_float(t1[1] << 16);
        o1.w = __uint_as_float(t1[1] & 0xffff0000u);
        float* pp = Pp + (size_t)qg * S_N + kt + lgrp * 8;
        *(float4*)pp = o0;
        *(float4*)(pp + 4) = o1;

        oacc[0] = __builtin_amdgcn_mfma_f32_16x16x32_bf16(ap, bv0, oacc[0], 0, 0, 0);
        oacc[1] = __builtin_amdgcn_mfma_f32_16x16x32_bf16(ap, bv1, oacc[1], 0, 0, 0);
        oacc[2] = __builtin_amdgcn_mfma_f32_16x16x32_bf16(ap, bv2, oacc[2], 0, 0, 0);
        oacc[3] = __builtin_amdgcn_mfma_f32_16x16x32_bf16(ap, bv3, oacc[3], 0, 0, 0);

        // Counted-vmcnt barrier: outstanding (issue order) =
        //   [P(t-1) x<=2][G(t+1) x4][P(t) x2] -> vmcnt(2): staging complete,
        //   2 newest (this iter's P stores) stay in flight across the barrier.
        asm volatile("s_waitcnt vmcnt(2)" ::: "memory");
        __builtin_amdgcn_s_barrier();
    }

    const int qb0 = qtile * 32 + wave * 16 + lgrp * 4;
#pragma unroll
    for (int db = 0; db < 4; ++db)
#pragma unroll
        for (int r = 0; r < 4; ++r)
            Op[(size_t)(qb0 + r) * D_N + db * 16 + l16] = oacc[db][r];
}

// ============================================================================
// Round-1 fallback (fp32 inputs, no workspace) — used only if ws too small.
// ============================================================================
__global__ __launch_bounds__(256)
void sdpa_fused(const float* __restrict__ Qg, const float* __restrict__ Kg,
                const float* __restrict__ Vg, float* __restrict__ Og,
                float* __restrict__ Pg)
{
    constexpr int LDP = 72;
    __shared__ bf16 K_lds [64][LDP];
    __shared__ bf16 Vt_lds[64][LDP];
    __shared__ bf16 P_lds [4][16][LDP];

    const int qtile = blockIdx.x;
    const int bh    = blockIdx.y;
    const int tid   = threadIdx.x;
    const int wave  = tid >> 6;
    const int lane  = tid & 63;
    const int l16   = lane & 15;
    const int lgrp  = lane >> 4;

    const float* Qp = Qg + (size_t)bh * S_N * D_N;
    const float* Kp = Kg + (size_t)bh * S_N * D_N;
    const float* Vp = Vg + (size_t)bh * S_N * D_N;
    float* Op = Og + (size_t)bh * S_N * D_N;
    float* Pp = Pg + (size_t)bh * S_N * S_N;

    const int qrow = qtile * 64 + wave * 16 + l16;
    bf16x8 aq[2];
#pragma unroll
    for (int ds = 0; ds < 2; ++ds) {
        const float* src = Qp + qrow * D_N + ds * 32 + lgrp * 8;
        float4 f0 = *(const float4*)(src);
        float4 f1 = *(const float4*)(src + 4);
        aq[ds][0] = (bf16)(f0.x * 0.125f); aq[ds][1] = (bf16)(f0.y * 0.125f);
        aq[ds][2] = (bf16)(f0.z * 0.125f); aq[ds][3] = (bf16)(f0.w * 0.125f);
        aq[ds][4] = (bf16)(f1.x * 0.125f); aq[ds][5] = (bf16)(f1.y * 0.125f);
        aq[ds][6] = (bf16)(f1.z * 0.125f); aq[ds][7] = (bf16)(f1.w * 0.125f);
    }

    auto stage_k = [&](int kt) {
#pragma unroll
        for (int i = 0; i < 4; ++i) {
            int slot = tid + i * 256;
            int row = slot >> 4, c4 = slot & 15;
            float4 f = *(const float4*)(Kp + (kt + row) * D_N + c4 * 4);
            bf16x4 pk = {(bf16)f.x, (bf16)f.y, (bf16)f.z, (bf16)f.w};
            *(bf16x4*)&K_lds[row][c4 * 4] = pk;
        }
    };
    auto stage_v = [&](int kt) {
#pragma unroll
        for (int i = 0; i < 4; ++i) {
            int slot = tid + i * 256;
            int row = slot >> 4, c4 = slot & 15;
            float4 f = *(const float4*)(Vp + (kt + row) * D_N + c4 * 4);
            Vt_lds[c4 * 4 + 0][row] = (bf16)f.x;
            Vt_lds[c4 * 4 + 1][row] = (bf16)f.y;
            Vt_lds[c4 * 4 + 2][row] = (bf16)f.z;
            Vt_lds[c4 * 4 + 3][row] = (bf16)f.w;
        }
    };
    auto compute_scores = [&](f32x4 (&acc)[4]) {
#pragma unroll
        for (int kb = 0; kb < 4; ++kb) {
            acc[kb] = (f32x4){0.f, 0.f, 0.f, 0.f};
#pragma unroll
            for (int ds = 0; ds < 2; ++ds) {
                bf16x8 bk = *(const bf16x8*)&K_lds[kb * 16 + l16][ds * 32 + lgrp * 8];
                acc[kb] = __builtin_amdgcn_mfma_f32_16x16x32_bf16(aq[ds], bk, acc[kb], 0, 0, 0);
            }
        }
    };

    float lsum[4] = {0.f, 0.f, 0.f, 0.f};
    for (int kt = 0; kt < S_N; kt += 64) {
        __syncthreads();
        stage_k(kt);
        __syncthreads();
        f32x4 acc[4];
        compute_scores(acc);
#pragma unroll
        for (int kb = 0; kb < 4; ++kb)
#pragma unroll
            for (int r = 0; r < 4; ++r) lsum[r] += __expf(acc[kb][r]);
    }
    float rl[4];
#pragma unroll
    for (int r = 0; r < 4; ++r) {
        float s = lsum[r];
        s += __shfl_xor(s, 1, 64);
        s += __shfl_xor(s, 2, 64);
        s += __shfl_xor(s, 4, 64);
        s += __shfl_xor(s, 8, 64);
        rl[r] = 1.0f / s;
    }

    f32x4 oacc[4];
#pragma unroll
    for (int db = 0; db < 4; ++db) oacc[db] = (f32x4){0.f, 0.f, 0.f, 0.f};
    const int qb0 = qtile * 64 + wave * 16 + lgrp * 4;

    for (int kt = 0; kt < S_N; kt += 64) {
        __syncthreads();
        stage_k(kt);
        stage_v(kt);
        __syncthreads();

        f32x4 acc[4];
        compute_scores(acc);
#pragma unroll
        for (int kb = 0; kb < 4; ++kb) {
#pragma unroll
            for (int r = 0; r < 4; ++r) {
                float p = __expf(acc[kb][r]) * rl[r];
                Pp[(size_t)(qb0 + r) * S_N + (kt + kb * 16 + l16)] = p;
                P_lds[wave][lgrp * 4 + r][kb * 16 + l16] = (bf16)p;
            }
        }
#pragma unroll
        for (int ks = 0; ks < 2; ++ks) {
            bf16x8 ap = *(const bf16x8*)&P_lds[wave][l16][ks * 32 + lgrp * 8];
#pragma unroll
            for (int db = 0; db < 4; ++db) {
                bf16x8 bv = *(const bf16x8*)&Vt_lds[db * 16 + l16][ks * 32 + lgrp * 8];
                oacc[db] = __builtin_amdgcn_mfma_f32_16x16x32_bf16(ap, bv, oacc[db], 0, 0, 0);
            }
        }
    }

#pragma unroll
    for (int db = 0; db < 4; ++db)
#pragma unroll
        for (int r = 0; r < 4; ++r)
            Op[(size_t)(qb0 + r) * D_N + db * 16 + l16] = oacc[db][r];
}

extern "C" void kernel_launch(void* const* d_in, const int* in_sizes, int n_in,
                              void* d_out, int out_size, void* d_ws, size_t ws_size,
                              hipStream_t stream) {
    const float* Q = (const float*)d_in[0];
    const float* K = (const float*)d_in[1];
    const float* V = (const float*)d_in[2];
    float* Out = (float*)d_out;                       // [4,16,1024,64]
    float* P   = (float*)d_out + (size_t)NELEM;       // [4,16,1024,1024]

    const size_t need = (size_t)NELEM * 2 * 2;        // Kb + Vt, bf16
    if (ws_size >= need) {
        bf16* Kb = (bf16*)d_ws;
        bf16* Vt = Kb + NELEM;
        prep_kv<<<dim3(4096), dim3(256), 0, stream>>>(K, V, Kb, Vt);
        sdpa_main<<<dim3(2048), dim3(128), 0, stream>>>(Q, Kb, Vt, Out, P);
    } else {
        sdpa_fused<<<dim3(16, 64), dim3(256), 0, stream>>>(Q, K, V, Out, P);
    }
}

// Round 14
// 96.555 us; speedup vs baseline: 1.1418x; 1.1418x over previous
//
#include <hip/hip_runtime.h>
#include <hip/hip_bf16.h>

// Problem constants (fixed by the reference): B=4, H=16, S=1024, D=64.
#define B_N 4
#define H_N 16
#define S_N 1024
#define D_N 64
#define NELEM (B_N * H_N * S_N * D_N)   // 4194304 elements per tensor

typedef __bf16 bf16;
typedef bf16  bf16x4 __attribute__((ext_vector_type(4)));
typedef bf16  bf16x8 __attribute__((ext_vector_type(8)));
typedef float f32x4  __attribute__((ext_vector_type(4)));
typedef unsigned int u32x2 __attribute__((ext_vector_type(2)));

#define AS1 __attribute__((address_space(1)))
#define AS3 __attribute__((address_space(3)))
// global->LDS DMA, 16B per lane; LDS dest = wave-uniform base + lane*16 (m104)
#define GLL16(gp, lp) __builtin_amdgcn_global_load_lds((const AS1 void*)(gp), (AS3 void*)(lp), 16, 0, 0)

// ============================================================================
// Prep (one kernel): fp32 -> bf16 swizzled copies of K and V into d_ws.
//  Kb[bh][k][d]  16B slots within each 128B row XORed by (k&7)
//  Vt[bh][d][k]  transposed; within each 64-k chunk, slots XORed by (d&7)
// ============================================================================
__global__ __launch_bounds__(256)
void prep_kv(const float* __restrict__ K, const float* __restrict__ V,
             bf16* __restrict__ Kb, bf16* __restrict__ Vt)
{
    const int b = blockIdx.x;
    if (b < 2048) {                        // ---- K: swizzled bf16 copy ----
        int t = b * 256 + threadIdx.x;     // 8 elems per thread
        int row = t >> 3, sub = t & 7;     // row = bh*S + k; sub = 16B slot
        const float* src = K + (size_t)row * 64 + sub * 8;
        float4 f0 = *(const float4*)src;
        float4 f1 = *(const float4*)(src + 4);
        bf16x8 o;
        o[0] = (bf16)f0.x; o[1] = (bf16)f0.y; o[2] = (bf16)f0.z; o[3] = (bf16)f0.w;
        o[4] = (bf16)f1.x; o[5] = (bf16)f1.y; o[6] = (bf16)f1.z; o[7] = (bf16)f1.w;
        int slot = sub ^ (row & 7);
        *(bf16x8*)(Kb + (size_t)row * 64 + slot * 8) = o;
    } else {                               // ---- V: transpose + swizzle ----
        int wid  = (b - 2048) * 4 + (threadIdx.x >> 6);
        int lane = threadIdx.x & 63;       // lane = d
        int bh = wid >> 7, chunk = wid & 127;   // 128 chunks of 8 k-rows
        const float* src = V + (size_t)bh * S_N * D_N + (size_t)chunk * 8 * 64 + lane;
        bf16x8 o;
#pragma unroll
        for (int j = 0; j < 8; ++j) o[j] = (bf16)src[j * 64];
        int slot = (chunk & 7) ^ (lane & 7);
        bf16* dst = Vt + (size_t)bh * D_N * S_N + (size_t)lane * S_N
                       + (chunk >> 3) * 64 + slot * 8;
        *(bf16x8*)dst = o;
    }
}

// ============================================================================
// Main fused kernel: 1 block = 64 q-rows (4 waves x 16), two passes over K.
// Round 14 = round 12 structure (counted vmcnt), with the P global-store path
// restructured for FULL-WIDTH transactions: two extra tr_reads per ks
// (region = 4j+lgrp, uniform per 16-lane group -> validated pattern class)
// give each lane 4 CONSECUTIVE k of its q-row; each store instruction is then
// 4 lanes x 16B contiguous per row (64B transactions, 4x fewer fragments).
// Old path: lane stored 2x16B at 32B stride -> fragmented L2 transactions.
// ============================================================================
__global__ __launch_bounds__(256)
void sdpa_main(const float* __restrict__ Qf, const bf16* __restrict__ Kb,
               const bf16* __restrict__ Vt, float* __restrict__ Og,
               float* __restrict__ Pg)
{
    __shared__ __attribute__((aligned(128))) bf16 K_lds[2][4096];   // 16KB
    __shared__ __attribute__((aligned(128))) bf16 V_lds[2][4096];   // 16KB
    __shared__ __attribute__((aligned(128))) bf16 Pt_lds[4][1024];  // 8KB

    // XCD-bijective swizzle: 16 q-tiles of each bh land on one XCD (nwg=1024%8==0)
    const int bid = blockIdx.x;
    const int swz = (bid & 7) * 128 + (bid >> 3);
    const int bh = swz >> 4, qtile = swz & 15;

    const int tid = threadIdx.x;
    const int wave = tid >> 6, lane = tid & 63;
    const int l16 = lane & 15, lgrp = lane >> 4;
    const int swx = (l16 & 7) << 4;     // byte XOR for swizzled LDS reads

    const float* Qp = Qf + (size_t)bh * S_N * D_N;
    const bf16* Kp = Kb + (size_t)bh * S_N * D_N;
    const bf16* Vp = Vt + (size_t)bh * D_N * S_N;
    float* Op = Og + (size_t)bh * S_N * D_N;
    float* Pp = Pg + (size_t)bh * S_N * S_N;

    // Q A-fragments from fp32, scaled by 1/sqrt(64): a[j]=Q[q=l16][k=lgrp*8+j]
    const int qrow = qtile * 64 + wave * 16 + l16;
    bf16x8 aq[2];
#pragma unroll
    for (int ds = 0; ds < 2; ++ds) {
        const float* src = Qp + (size_t)qrow * 64 + ds * 32 + lgrp * 8;
        float4 f0 = *(const float4*)src;
        float4 f1 = *(const float4*)(src + 4);
        aq[ds][0] = (bf16)(f0.x * 0.125f); aq[ds][1] = (bf16)(f0.y * 0.125f);
        aq[ds][2] = (bf16)(f0.z * 0.125f); aq[ds][3] = (bf16)(f0.w * 0.125f);
        aq[ds][4] = (bf16)(f1.x * 0.125f); aq[ds][5] = (bf16)(f1.y * 0.125f);
        aq[ds][6] = (bf16)(f1.z * 0.125f); aq[ds][7] = (bf16)(f1.w * 0.125f);
    }

    // Staging: one 64x64 bf16 tile = 8KB = 2 GLL16 per wave (4 waves)
    auto stage_k = [&](int kt, bf16* dst) {
        const bf16* gk = Kp + (size_t)kt * 64;
        GLL16(gk + (wave    ) * 512 + lane * 8, dst + (wave    ) * 512);
        GLL16(gk + (wave + 4) * 512 + lane * 8, dst + (wave + 4) * 512);
    };
    // 128-k double tile (16KB contiguous) into two 8KB buffers
    auto stage_k2 = [&](int kt, bf16* dst0, bf16* dst1) {
        const bf16* gk = Kp + (size_t)kt * 64;
        GLL16(gk + (wave     ) * 512 + lane * 8, dst0 + (wave    ) * 512);
        GLL16(gk + (wave + 4 ) * 512 + lane * 8, dst0 + (wave + 4) * 512);
        GLL16(gk + (wave + 8 ) * 512 + lane * 8, dst1 + (wave    ) * 512);
        GLL16(gk + (wave + 12) * 512 + lane * 8, dst1 + (wave + 4) * 512);
    };
    auto stage_v = [&](int kt, bf16* dst) {
        const int dr = lane >> 3, c7 = lane & 7;   // rows are d, 128B slices
        GLL16(Vp + (size_t)((wave    ) * 8 + dr) * S_N + kt + c7 * 8, dst + (wave    ) * 512);
        GLL16(Vp + (size_t)((wave + 4) * 8 + dr) * S_N + kt + c7 * 8, dst + (wave + 4) * 512);
    };

    // QK^T scores for this wave's 16 q-rows vs a staged 64-row K tile.
    // C/D layout (m89): col(k) = lane&15, row(q) = (lane>>4)*4 + reg.
    auto scores = [&](const bf16* base, f32x4 (&acc)[4]) {
#pragma unroll
        for (int kb = 0; kb < 4; ++kb) {
            acc[kb] = (f32x4){0.f, 0.f, 0.f, 0.f};
#pragma unroll
            for (int ds = 0; ds < 2; ++ds) {
                bf16x8 bk = *(const bf16x8*)((const char*)base
                            + (kb * 16 + l16) * 128
                            + ((ds * 64 + lgrp * 16) ^ swx));
                acc[kb] = __builtin_amdgcn_mfma_f32_16x16x32_bf16(aq[ds], bk, acc[kb], 0, 0, 0);
            }
        }
    };

    // -------- Pass A: denominators. 128 k per iter, 1 barrier per iter. -----
    float lsum[4] = {0.f, 0.f, 0.f, 0.f};
    stage_k2(0, &K_lds[0][0], &K_lds[1][0]);
    __syncthreads();
    for (int c = 0; c < 8; ++c) {
        const bf16* b0 = (c & 1) ? &V_lds[0][0] : &K_lds[0][0];
        const bf16* b1 = (c & 1) ? &V_lds[1][0] : &K_lds[1][0];
        bf16* n0 = (c & 1) ? &K_lds[0][0] : &V_lds[0][0];
        bf16* n1 = (c & 1) ? &K_lds[1][0] : &V_lds[1][0];
        if (c < 7) stage_k2((c + 1) * 128, n0, n1);
        f32x4 acc[4];
        scores(b0, acc);
#pragma unroll
        for (int kb = 0; kb < 4; ++kb)
#pragma unroll
            for (int r = 0; r < 4; ++r) lsum[r] += __expf(acc[kb][r]);
        scores(b1, acc);
#pragma unroll
        for (int kb = 0; kb < 4; ++kb)
#pragma unroll
            for (int r = 0; r < 4; ++r) lsum[r] += __expf(acc[kb][r]);
        __syncthreads();
    }
    float rl[4];
#pragma unroll
    for (int r = 0; r < 4; ++r) {
        float s = lsum[r];
        s += __shfl_xor(s, 1, 64);
        s += __shfl_xor(s, 2, 64);
        s += __shfl_xor(s, 4, 64);
        s += __shfl_xor(s, 8, 64);
        rl[r] = 1.0f / s;
    }

    // ---- Pass B: recompute, write P, accumulate O = P V. 1 barrier/iter, ---
    // ---- counted vmcnt: P stores stay in flight across the barrier.     ----
    f32x4 oacc[4];
#pragma unroll
    for (int db = 0; db < 4; ++db) oacc[db] = (f32x4){0.f, 0.f, 0.f, 0.f};

    const unsigned ptoff = (unsigned)(uintptr_t)(AS3 bf16*)(&Pt_lds[wave][0]);
    const int qg = qtile * 64 + wave * 16 + l16;

    stage_k(0, &K_lds[0][0]);
    stage_v(0, &V_lds[0][0]);
    asm volatile("s_waitcnt vmcnt(0)" ::: "memory");
    __builtin_amdgcn_s_barrier();
    for (int t = 0; t < 16; ++t) {
        const int kt = t * 64, buf = t & 1;

        f32x4 acc[4];
        scores(&K_lds[buf][0], acc);

        // Prefetch t+1 (issued before this iter's P stores; in-order vmcnt
        // lets the barrier wait complete staging without draining stores).
        if (t < 15) {
            stage_k(kt + 64, &K_lds[buf ^ 1][0]);
            stage_v(kt + 64, &V_lds[buf ^ 1][0]);
        }

        // p = exp(s)*rl -> bf16; write P^T[k][q] as packed 4-q ds_write_b64
#pragma unroll
        for (int kb = 0; kb < 4; ++kb) {
            bf16x4 pk;
#pragma unroll
            for (int r = 0; r < 4; ++r) pk[r] = (bf16)(__expf(acc[kb][r]) * rl[r]);
            *(bf16x4*)((char*)&Pt_lds[wave][0] + (kb * 16 + l16) * 32 + lgrp * 8) = pk;
        }
        asm volatile("s_waitcnt lgkmcnt(0)" ::: "memory");  // writes done before tr reads

        const bf16* vb = &V_lds[buf][0];
#pragma unroll
        for (int ks = 0; ks < 2; ++ks) {
            // V B-fragments (swizzled row-major [d][k] reads, 2-way free)
            bf16x8 bv0 = *(const bf16x8*)((const char*)vb + (l16     ) * 128 + ((ks * 64 + lgrp * 16) ^ swx));
            bf16x8 bv1 = *(const bf16x8*)((const char*)vb + (16 + l16) * 128 + ((ks * 64 + lgrp * 16) ^ swx));
            bf16x8 bv2 = *(const bf16x8*)((const char*)vb + (32 + l16) * 128 + ((ks * 64 + lgrp * 16) ^ swx));
            bf16x8 bv3 = *(const bf16x8*)((const char*)vb + (48 + l16) * 128 + ((ks * 64 + lgrp * 16) ^ swx));

            // Four tr_reads, all with region uniform per 16-lane group (the
            // validated class):
            //  PV A-frag: regions 2*lgrp, 2*lgrp+1 (addr a, a+offset:128)
            //  store path: regions lgrp, lgrp+4 (addr b, b+512) -> lane gets
            //  4 CONSECUTIVE k (=4*region..+3) of row q=l16 as 4 bf16 in 8B.
            u32x2 t0, t1, s0, s1;
            unsigned a = ptoff + ks * 1024 + lgrp * 256 + l16 * 8;
            unsigned b = ptoff + ks * 1024 + lgrp * 128 + l16 * 8;
            asm volatile("ds_read_b64_tr_b16 %0, %4\n\t"
                         "ds_read_b64_tr_b16 %1, %4 offset:128\n\t"
                         "ds_read_b64_tr_b16 %2, %5\n\t"
                         "ds_read_b64_tr_b16 %3, %6"
                         : "=&v"(t0), "=&v"(t1), "=&v"(s0), "=&v"(s1)
                         : "v"(a), "v"(b), "v"(b + 512));
            asm volatile("s_waitcnt lgkmcnt(0)" ::: "memory");
            __builtin_amdgcn_sched_barrier(0);   // rule 18: keep consumers below the wait

            bf16x8 ap;
            ((unsigned*)&ap)[0] = t0[0]; ((unsigned*)&ap)[1] = t0[1];
            ((unsigned*)&ap)[2] = t1[0]; ((unsigned*)&ap)[3] = t1[1];

            // Full-width P store: instruction j covers, per q-row, 4 lanes x
            // 16B CONTIGUOUS (k = 16j + lgrp*4 .. +4) -> 64B transactions.
            float4 oA, oB;
            oA.x = __uint_as_float(s0[0] << 16);
            oA.y = __uint_as_float(s0[0] & 0xffff0000u);
            oA.z = __uint_as_float(s0[1] << 16);
            oA.w = __uint_as_float(s0[1] & 0xffff0000u);
            oB.x = __uint_as_float(s1[0] << 16);
            oB.y = __uint_as_float(s1[0] & 0xffff0000u);
            oB.z = __uint_as_float(s1[1] << 16);
            oB.w = __uint_as_float(s1[1] & 0xffff0000u);
            float* pp = Pp + (size_t)qg * S_N + kt + ks * 32 + lgrp * 4;
            *(float4*)pp = oA;
            *(float4*)(pp + 16) = oB;

            oacc[0] = __builtin_amdgcn_mfma_f32_16x16x32_bf16(ap, bv0, oacc[0], 0, 0, 0);
            oacc[1] = __builtin_amdgcn_mfma_f32_16x16x32_bf16(ap, bv1, oacc[1], 0, 0, 0);
            oacc[2] = __builtin_amdgcn_mfma_f32_16x16x32_bf16(ap, bv2, oacc[2], 0, 0, 0);
            oacc[3] = __builtin_amdgcn_mfma_f32_16x16x32_bf16(ap, bv3, oacc[3], 0, 0, 0);
        }

        // Counted-vmcnt barrier: outstanding (issue order) =
        //   [P(t-1) maybe][GLL16(t+1) x4][P(t) x4] -> vmcnt(4): staging
        //   complete, this iter's 4 P stores stay in flight across barrier.
        asm volatile("s_waitcnt vmcnt(4)" ::: "memory");
        __builtin_amdgcn_s_barrier();
    }

    const int qb0 = qtile * 64 + wave * 16 + lgrp * 4;
#pragma unroll
    for (int db = 0; db < 4; ++db)
#pragma unroll
        for (int r = 0; r < 4; ++r)
            Op[(size_t)(qb0 + r) * D_N + db * 16 + l16] = oacc[db][r];
}

// ============================================================================
// Round-1 fallback (fp32 inputs, no workspace) — used only if ws too small.
// ============================================================================
__global__ __launch_bounds__(256)
void sdpa_fused(const float* __restrict__ Qg, const float* __restrict__ Kg,
                const float* __restrict__ Vg, float* __restrict__ Og,
                float* __restrict__ Pg)
{
    constexpr int LDP = 72;
    __shared__ bf16 K_lds [64][LDP];
    __shared__ bf16 Vt_lds[64][LDP];
    __shared__ bf16 P_lds [4][16][LDP];

    const int qtile = blockIdx.x;
    const int bh    = blockIdx.y;
    const int tid   = threadIdx.x;
    const int wave  = tid >> 6;
    const int lane  = tid & 63;
    const int l16   = lane & 15;
    const int lgrp  = lane >> 4;

    const float* Qp = Qg + (size_t)bh * S_N * D_N;
    const float* Kp = Kg + (size_t)bh * S_N * D_N;
    const float* Vp = Vg + (size_t)bh * S_N * D_N;
    float* Op = Og + (size_t)bh * S_N * D_N;
    float* Pp = Pg + (size_t)bh * S_N * S_N;

    const int qrow = qtile * 64 + wave * 16 + l16;
    bf16x8 aq[2];
#pragma unroll
    for (int ds = 0; ds < 2; ++ds) {
        const float* src = Qp + qrow * D_N + ds * 32 + lgrp * 8;
        float4 f0 = *(const float4*)(src);
        float4 f1 = *(const float4*)(src + 4);
        aq[ds][0] = (bf16)(f0.x * 0.125f); aq[ds][1] = (bf16)(f0.y * 0.125f);
        aq[ds][2] = (bf16)(f0.z * 0.125f); aq[ds][3] = (bf16)(f0.w * 0.125f);
        aq[ds][4] = (bf16)(f1.x * 0.125f); aq[ds][5] = (bf16)(f1.y * 0.125f);
        aq[ds][6] = (bf16)(f1.z * 0.125f); aq[ds][7] = (bf16)(f1.w * 0.125f);
    }

    auto stage_k = [&](int kt) {
#pragma unroll
        for (int i = 0; i < 4; ++i) {
            int slot = tid + i * 256;
            int row = slot >> 4, c4 = slot & 15;
            float4 f = *(const float4*)(Kp + (kt + row) * D_N + c4 * 4);
            bf16x4 pk = {(bf16)f.x, (bf16)f.y, (bf16)f.z, (bf16)f.w};
            *(bf16x4*)&K_lds[row][c4 * 4] = pk;
        }
    };
    auto stage_v = [&](int kt) {
#pragma unroll
        for (int i = 0; i < 4; ++i) {
            int slot = tid + i * 256;
            int row = slot >> 4, c4 = slot & 15;
            float4 f = *(const float4*)(Vp + (kt + row) * D_N + c4 * 4);
            Vt_lds[c4 * 4 + 0][row] = (bf16)f.x;
            Vt_lds[c4 * 4 + 1][row] = (bf16)f.y;
            Vt_lds[c4 * 4 + 2][row] = (bf16)f.z;
            Vt_lds[c4 * 4 + 3][row] = (bf16)f.w;
        }
    };
    auto compute_scores = [&](f32x4 (&acc)[4]) {
#pragma unroll
        for (int kb = 0; kb < 4; ++kb) {
            acc[kb] = (f32x4){0.f, 0.f, 0.f, 0.f};
#pragma unroll
            for (int ds = 0; ds < 2; ++ds) {
                bf16x8 bk = *(const bf16x8*)&K_lds[kb * 16 + l16][ds * 32 + lgrp * 8];
                acc[kb] = __builtin_amdgcn_mfma_f32_16x16x32_bf16(aq[ds], bk, acc[kb], 0, 0, 0);
            }
        }
    };

    float lsum[4] = {0.f, 0.f, 0.f, 0.f};
    for (int kt = 0; kt < S_N; kt += 64) {
        __syncthreads();
        stage_k(kt);
        __syncthreads();
        f32x4 acc[4];
        compute_scores(acc);
#pragma unroll
        for (int kb = 0; kb < 4; ++kb)
#pragma unroll
            for (int r = 0; r < 4; ++r) lsum[r] += __expf(acc[kb][r]);
    }
    float rl[4];
#pragma unroll
    for (int r = 0; r < 4; ++r) {
        float s = lsum[r];
        s += __shfl_xor(s, 1, 64);
        s += __shfl_xor(s, 2, 64);
        s += __shfl_xor(s, 4, 64);
        s += __shfl_xor(s, 8, 64);
        rl[r] = 1.0f / s;
    }

    f32x4 oacc[4];
#pragma unroll
    for (int db = 0; db < 4; ++db) oacc[db] = (f32x4){0.f, 0.f, 0.f, 0.f};
    const int qb0 = qtile * 64 + wave * 16 + lgrp * 4;

    for (int kt = 0; kt < S_N; kt += 64) {
        __syncthreads();
        stage_k(kt);
        stage_v(kt);
        __syncthreads();

        f32x4 acc[4];
        compute_scores(acc);
#pragma unroll
        for (int kb = 0; kb < 4; ++kb) {
#pragma unroll
            for (int r = 0; r < 4; ++r) {
                float p = __expf(acc[kb][r]) * rl[r];
                Pp[(size_t)(qb0 + r) * S_N + (kt + kb * 16 + l16)] = p;
                P_lds[wave][lgrp * 4 + r][kb * 16 + l16] = (bf16)p;
            }
        }
#pragma unroll
        for (int ks = 0; ks < 2; ++ks) {
            bf16x8 ap = *(const bf16x8*)&P_lds[wave][l16][ks * 32 + lgrp * 8];
#pragma unroll
            for (int db = 0; db < 4; ++db) {
                bf16x8 bv = *(const bf16x8*)&Vt_lds[db * 16 + l16][ks * 32 + lgrp * 8];
                oacc[db] = __builtin_amdgcn_mfma_f32_16x16x32_bf16(ap, bv, oacc[db], 0, 0, 0);
            }
        }
    }

#pragma unroll
    for (int db = 0; db < 4; ++db)
#pragma unroll
        for (int r = 0; r < 4; ++r)
            Op[(size_t)(qb0 + r) * D_N + db * 16 + l16] = oacc[db][r];
}

extern "C" void kernel_launch(void* const* d_in, const int* in_sizes, int n_in,
                              void* d_out, int out_size, void* d_ws, size_t ws_size,
                              hipStream_t stream) {
    const float* Q = (const float*)d_in[0];
    const float* K = (const float*)d_in[1];
    const float* V = (const float*)d_in[2];
    float* Out = (float*)d_out;                       // [4,16,1024,64]
    float* P   = (float*)d_out + (size_t)NELEM;       // [4,16,1024,1024]

    const size_t need = (size_t)NELEM * 2 * 2;        // Kb + Vt, bf16
    if (ws_size >= need) {
        bf16* Kb = (bf16*)d_ws;
        bf16* Vt = Kb + NELEM;
        prep_kv<<<dim3(4096), dim3(256), 0, stream>>>(K, V, Kb, Vt);
        sdpa_main<<<dim3(1024), dim3(256), 0, stream>>>(Q, Kb, Vt, Out, P);
    } else {
        sdpa_fused<<<dim3(16, 64), dim3(256), 0, stream>>>(Q, K, V, Out, P);
    }
}